// Round 1
// baseline (1650.205 us; speedup 1.0000x reference)
//
#include <hip/hip_runtime.h>

typedef __bf16 bf16;
typedef __bf16 bf16x8 __attribute__((ext_vector_type(8)));
typedef float f32x4 __attribute__((ext_vector_type(4)));

#define L_SEQ   2048
#define D_MODEL 3072
#define N_HEADS 24
#define N1      21504   // QKV + 4D  (gemm1 N)
#define QKV_N   9216
#define CC      15360   // D + 4D    (gemm2 K / concat width)

// ---------------- workspace layout (bytes) ----------------
// m_buf   @ 0          : 9216 f32 (shift|scale|gate)
// x_mod   @ 36864      : 2048x3072 bf16   (LN+modulated, GEMM1 A)
// w1t     @ 12619776   : 21504x3072 bf16  (w1 transposed; later reused for w2t 3072x15360)
// hqkv    @ 144740352  : 2048x9216 bf16   (raw qkv part of h)
// concat  @ 182489088  : 2048x15360 bf16  (attn | gelu(mlp)) = GEMM2 A
// q_r     @ 245403648  : 24x2048x128 bf16 (post rms+rope)
// k_r     @ 257986560  : 24x2048x128 bf16
// v_t     @ 270569472  : 24x128x2048 bf16 (V transposed per head)
// total ~283.2 MB

__device__ __forceinline__ void async_cp16(const void* g, void* s) {
    __builtin_amdgcn_global_load_lds((const __attribute__((address_space(1))) void*)g,
                                     (__attribute__((address_space(3))) void*)s, 16, 0, 0);
}

// ---------------- modulation GEMV ----------------
__global__ __launch_bounds__(256) void mod_init_kernel(const float* __restrict__ b_mod, float* __restrict__ m) {
    int j = blockIdx.x * 256 + threadIdx.x;
    m[j] = b_mod[j];
}

__global__ __launch_bounds__(256) void mod_gemv_kernel(const float* __restrict__ vec,
                                                       const float* __restrict__ w_mod,
                                                       float* __restrict__ m) {
    int j  = blockIdx.x * 256 + threadIdx.x;
    int d0 = blockIdx.y * 256;
    __shared__ float sv[256];
    float x = vec[d0 + threadIdx.x];
    sv[threadIdx.x] = x / (1.f + __expf(-x));   // silu
    __syncthreads();
    float acc = 0.f;
    #pragma unroll 8
    for (int d = 0; d < 256; d++)
        acc += sv[d] * w_mod[(size_t)(d0 + d) * QKV_N + j];
    atomicAdd(&m[j], acc);
}

// ---------------- layernorm + modulation -> bf16 ----------------
__global__ __launch_bounds__(256) void ln_kernel(const float* __restrict__ x,
                                                 const float* __restrict__ m,
                                                 bf16* __restrict__ x_mod) {
    int l = blockIdx.x, tid = threadIdx.x;
    const float4* xr = (const float4*)(x + (size_t)l * D_MODEL);
    float4 v[3];
    float s = 0.f, ss = 0.f;
    #pragma unroll
    for (int p = 0; p < 3; p++) {
        v[p] = xr[p * 256 + tid];
        s  += v[p].x + v[p].y + v[p].z + v[p].w;
        ss += v[p].x * v[p].x + v[p].y * v[p].y + v[p].z * v[p].z + v[p].w * v[p].w;
    }
    #pragma unroll
    for (int off = 32; off; off >>= 1) { s += __shfl_xor(s, off); ss += __shfl_xor(ss, off); }
    __shared__ float rs[4], rss[4];
    int wave = tid >> 6, lane = tid & 63;
    if (lane == 0) { rs[wave] = s; rss[wave] = ss; }
    __syncthreads();
    s  = rs[0] + rs[1] + rs[2] + rs[3];
    ss = rss[0] + rss[1] + rss[2] + rss[3];
    float mu   = s * (1.f / D_MODEL);
    float var  = ss * (1.f / D_MODEL) - mu * mu;
    float rstd = rsqrtf(var + 1e-6f);
    #pragma unroll
    for (int p = 0; p < 3; p++) {
        int c = (p * 256 + tid) * 4;
        const float* ve = (const float*)&v[p];
        union { bf16 b[4]; uint2 u; } pk;
        #pragma unroll
        for (int e = 0; e < 4; e++) {
            float xn = (ve[e] - mu) * rstd;
            pk.b[e] = (bf16)((1.f + m[D_MODEL + c + e]) * xn + m[c + e]);
        }
        *(uint2*)(x_mod + (size_t)l * D_MODEL + c) = pk.u;
    }
}

// ---------------- transpose + f32->bf16 convert: in (R,C) f32 -> out (C,R) bf16 ----------------
__global__ __launch_bounds__(256) void tconv_kernel(const float* __restrict__ in, bf16* __restrict__ out,
                                                    int R, int C) {
    __shared__ float T[64][65];
    int c0 = blockIdx.x * 64, r0 = blockIdx.y * 64;
    int tid = threadIdx.x;
    int col4 = (tid & 15) * 4, rr = tid >> 4;
    #pragma unroll
    for (int p = 0; p < 4; p++) {
        int r = rr + p * 16;
        float4 v = *(const float4*)(in + (size_t)(r0 + r) * C + c0 + col4);
        T[r][col4 + 0] = v.x; T[r][col4 + 1] = v.y; T[r][col4 + 2] = v.z; T[r][col4 + 3] = v.w;
    }
    __syncthreads();
    int c = tid >> 2, rq = (tid & 3) * 16;
    union { bf16 b[16]; uint4 u[2]; } pk;
    #pragma unroll
    for (int i = 0; i < 16; i++) pk.b[i] = (bf16)T[rq + i][c];
    uint4* op = (uint4*)(out + (size_t)(c0 + c) * R + r0 + rq);
    op[0] = pk.u[0]; op[1] = pk.u[1];
}

// ---------------- m97-style 128x128 bf16 GEMM, Bt is (N,K) ----------------
// EPI=1: h = A@W1+b1 -> split qkv / gelu(mlp)->concat ; EPI=2: out = x + gate*(A@W2+b2)
template <int EPI>
__global__ __launch_bounds__(256) void gemm_kernel(
    const bf16* __restrict__ A, const bf16* __restrict__ Bt,
    const float* __restrict__ bias, int K,
    bf16* __restrict__ o_qkv, bf16* __restrict__ o_concat,
    const float* __restrict__ xres, const float* __restrict__ gate,
    float* __restrict__ out) {
    __shared__ bf16 As[128 * 32];
    __shared__ bf16 Bs[128 * 32];
    const int tid = threadIdx.x;
    const int wave = tid >> 6, lane = tid & 63;
    const int l16 = lane & 15, lq = lane >> 4;
    const int wm = (wave >> 1) * 64, wn = (wave & 1) * 64;
    const int m0 = blockIdx.y * 128, n0 = blockIdx.x * 128;

    const int srow  = wave * 16 + (lane >> 2);
    const int skoff = (lane & 3) * 8;
    const bf16* Ag = A  + (size_t)(m0 + srow) * K + skoff;
    const bf16* Bg = Bt + (size_t)(n0 + srow) * K + skoff;
    bf16* As_w = As + wave * 16 * 32;   // wave-uniform LDS base; HW scatters lane*16B
    bf16* Bs_w = Bs + wave * 16 * 32;

    f32x4 acc[4][4];
    #pragma unroll
    for (int i = 0; i < 4; i++)
        #pragma unroll
        for (int j = 0; j < 4; j++) acc[i][j] = f32x4{0.f, 0.f, 0.f, 0.f};

    for (int k0 = 0; k0 < K; k0 += 32) {
        __syncthreads();
        async_cp16(Ag + k0,                   As_w);
        async_cp16(Ag + k0 + (size_t)64 * K,  As_w + 64 * 32);
        async_cp16(Bg + k0,                   Bs_w);
        async_cp16(Bg + k0 + (size_t)64 * K,  Bs_w + 64 * 32);
        __syncthreads();
        bf16x8 af[4], bfr[4];
        #pragma unroll
        for (int i = 0; i < 4; i++) af[i]  = *(const bf16x8*)(As + (wm + 16 * i + l16) * 32 + lq * 8);
        #pragma unroll
        for (int j = 0; j < 4; j++) bfr[j] = *(const bf16x8*)(Bs + (wn + 16 * j + l16) * 32 + lq * 8);
        #pragma unroll
        for (int i = 0; i < 4; i++)
            #pragma unroll
            for (int j = 0; j < 4; j++)
                acc[i][j] = __builtin_amdgcn_mfma_f32_16x16x32_bf16(af[i], bfr[j], acc[i][j], 0, 0, 0);
    }

    #pragma unroll
    for (int i = 0; i < 4; i++) {
        int row = m0 + wm + 16 * i + lq * 4;
        #pragma unroll
        for (int j = 0; j < 4; j++) {
            int col = n0 + wn + 16 * j + l16;
            float bv = bias[col];
            #pragma unroll
            for (int r = 0; r < 4; r++) {
                float v = acc[i][j][r] + bv;
                int rr = row + r;
                if (EPI == 1) {
                    if (col < QKV_N) {
                        o_qkv[(size_t)rr * QKV_N + col] = (bf16)v;
                    } else {
                        float g = 0.5f * v * (1.f + tanhf(0.7978845608028654f * (v + 0.044715f * v * v * v)));
                        o_concat[(size_t)rr * CC + (col - QKV_N + D_MODEL)] = (bf16)g;
                    }
                } else {
                    size_t idx = (size_t)rr * D_MODEL + col;
                    out[idx] = xres[idx] + gate[col] * v;
                }
            }
        }
    }
}

// ---------------- RMSNorm + RoPE for q,k: one wave per (l,head) row ----------------
__global__ __launch_bounds__(256) void qkv_rope_kernel(const bf16* __restrict__ hqkv,
                                                       const float* __restrict__ pe,
                                                       const float* __restrict__ q_scale,
                                                       const float* __restrict__ k_scale,
                                                       bf16* __restrict__ q_r, bf16* __restrict__ k_r) {
    int wave = threadIdx.x >> 6, lane = threadIdx.x & 63;
    int idx = blockIdx.x * 4 + wave;          // 0 .. 2048*24-1
    int l = idx / N_HEADS, h = idx - l * N_HEADS;
    const bf16* qg = hqkv + (size_t)l * QKV_N + h * 128;
    const bf16* kg = qg + D_MODEL;
    float q0 = (float)qg[2 * lane], q1 = (float)qg[2 * lane + 1];
    float k0 = (float)kg[2 * lane], k1 = (float)kg[2 * lane + 1];
    float sq = q0 * q0 + q1 * q1, sk = k0 * k0 + k1 * k1;
    #pragma unroll
    for (int off = 32; off; off >>= 1) { sq += __shfl_xor(sq, off); sk += __shfl_xor(sk, off); }
    float rq = rsqrtf(sq * (1.f / 128.f) + 1e-6f);
    float rk = rsqrtf(sk * (1.f / 128.f) + 1e-6f);
    float s0 = q_scale[2 * lane], s1 = q_scale[2 * lane + 1];
    float z0 = k_scale[2 * lane], z1 = k_scale[2 * lane + 1];
    float4 p = ((const float4*)pe)[(size_t)l * 64 + lane];   // {pe[i,0,0], pe[i,0,1], pe[i,1,0], pe[i,1,1]}
    float tq0 = q0 * rq * s0, tq1 = q1 * rq * s1;
    float tk0 = k0 * rk * z0, tk1 = k1 * rk * z1;
    size_t ob = ((size_t)h * L_SEQ + l) * 128 + 2 * lane;
    q_r[ob]     = (bf16)(p.x * tq0 + p.y * tq1);
    q_r[ob + 1] = (bf16)(p.z * tq0 + p.w * tq1);
    k_r[ob]     = (bf16)(p.x * tk0 + p.y * tk1);
    k_r[ob + 1] = (bf16)(p.z * tk0 + p.w * tk1);
}

// ---------------- V transpose: hqkv v-part (l, h*128+d) -> v_t (h, d, l) ----------------
__global__ __launch_bounds__(256) void vtrans_kernel(const bf16* __restrict__ hqkv, bf16* __restrict__ v_t) {
    int dt = blockIdx.x * 64, lt = blockIdx.y * 64, h = blockIdx.z;
    __shared__ bf16 T[64][72];
    int tid = threadIdx.x;
    #pragma unroll
    for (int p = 0; p < 2; p++) {
        int idx = p * 256 + tid;
        int r = idx >> 3, c = idx & 7;   // r: l-local, c: 8-elem d chunk
        uint4 v = *(const uint4*)(hqkv + (size_t)(lt + r) * QKV_N + 2 * D_MODEL + h * 128 + dt + c * 8);
        *(uint4*)(&T[r][c * 8]) = v;
    }
    __syncthreads();
    #pragma unroll
    for (int p = 0; p < 2; p++) {
        int idx = p * 256 + tid;
        int d = idx >> 3, c = idx & 7;   // d: d-local row, c: 8-elem l chunk
        union { bf16 b[8]; uint4 u; } pk;
        #pragma unroll
        for (int i = 0; i < 8; i++) pk.b[i] = T[c * 8 + i][d];
        *(uint4*)(v_t + ((size_t)h * 128 + dt + d) * L_SEQ + lt + c * 8) = pk.u;
    }
}

// ---------------- flash attention: one block per (head, 64 q rows) ----------------
__global__ __launch_bounds__(256) void attn_kernel(const bf16* __restrict__ q_r, const bf16* __restrict__ k_r,
                                                   const bf16* __restrict__ v_t, bf16* __restrict__ concat) {
    const int h = blockIdx.y;
    const int q0 = blockIdx.x * 64;
    __shared__ bf16 Qs[64 * 128];
    __shared__ bf16 Ks[64 * 128];
    __shared__ bf16 Vs[128 * 64];   // V^T tile: [d][key]
    __shared__ bf16 Ps[64 * 64];
    const int tid = threadIdx.x, wave = tid >> 6, lane = tid & 63;
    const int l16 = lane & 15, lq = lane >> 4;
    const bf16* Qg = q_r + ((size_t)h * L_SEQ + q0) * 128;
    const bf16* Kg = k_r + (size_t)h * L_SEQ * 128;
    const bf16* Vg = v_t + (size_t)h * 128 * L_SEQ;
    #pragma unroll
    for (int p = 0; p < 4; p++) {
        int idx = p * 256 + tid, r = idx >> 4, c = idx & 15;
        *(uint4*)(Qs + r * 128 + c * 8) = *(const uint4*)(Qg + (size_t)r * 128 + c * 8);
    }
    f32x4 accO[8];
    #pragma unroll
    for (int i = 0; i < 8; i++) accO[i] = f32x4{0.f, 0.f, 0.f, 0.f};
    float mrow[4] = {-1e30f, -1e30f, -1e30f, -1e30f};
    float lrow[4] = {0.f, 0.f, 0.f, 0.f};
    const float sc = 0.08838834764831845f;   // 128^-0.5
    for (int kt = 0; kt < 32; kt++) {
        __syncthreads();
        const bf16* Kt = Kg + (size_t)kt * 64 * 128;
        const bf16* Vt = Vg + kt * 64;
        #pragma unroll
        for (int p = 0; p < 4; p++) {
            int idx = p * 256 + tid, r = idx >> 4, c = idx & 15;
            *(uint4*)(Ks + r * 128 + c * 8) = *(const uint4*)(Kt + (size_t)r * 128 + c * 8);
        }
        #pragma unroll
        for (int p = 0; p < 4; p++) {
            int idx = p * 256 + tid, r = idx >> 3, c = idx & 7;
            *(uint4*)(Vs + r * 64 + c * 8) = *(const uint4*)(Vt + (size_t)r * L_SEQ + c * 8);
        }
        __syncthreads();
        f32x4 accS[4];
        #pragma unroll
        for (int i = 0; i < 4; i++) accS[i] = f32x4{0.f, 0.f, 0.f, 0.f};
        #pragma unroll
        for (int kk = 0; kk < 4; kk++) {
            bf16x8 a = *(const bf16x8*)(Qs + (wave * 16 + l16) * 128 + kk * 32 + lq * 8);
            #pragma unroll
            for (int nt = 0; nt < 4; nt++) {
                bf16x8 b = *(const bf16x8*)(Ks + (nt * 16 + l16) * 128 + kk * 32 + lq * 8);
                accS[nt] = __builtin_amdgcn_mfma_f32_16x16x32_bf16(a, b, accS[nt], 0, 0, 0);
            }
        }
        float alpha[4];
        #pragma unroll
        for (int r = 0; r < 4; r++) {
            float x0 = accS[0][r] * sc, x1 = accS[1][r] * sc, x2 = accS[2][r] * sc, x3 = accS[3][r] * sc;
            float mx = fmaxf(fmaxf(x0, x1), fmaxf(x2, x3));
            #pragma unroll
            for (int off = 1; off < 16; off <<= 1) mx = fmaxf(mx, __shfl_xor(mx, off));
            float mnew = fmaxf(mrow[r], mx);
            alpha[r] = __expf(mrow[r] - mnew);
            float p0 = __expf(x0 - mnew), p1 = __expf(x1 - mnew);
            float p2 = __expf(x2 - mnew), p3 = __expf(x3 - mnew);
            float rsum = p0 + p1 + p2 + p3;
            #pragma unroll
            for (int off = 1; off < 16; off <<= 1) rsum += __shfl_xor(rsum, off);
            lrow[r] = lrow[r] * alpha[r] + rsum;
            mrow[r] = mnew;
            int prow = wave * 16 + lq * 4 + r;
            Ps[prow * 64 +  0 + l16] = (bf16)p0;
            Ps[prow * 64 + 16 + l16] = (bf16)p1;
            Ps[prow * 64 + 32 + l16] = (bf16)p2;
            Ps[prow * 64 + 48 + l16] = (bf16)p3;
        }
        #pragma unroll
        for (int i = 0; i < 8; i++) {
            accO[i][0] *= alpha[0]; accO[i][1] *= alpha[1];
            accO[i][2] *= alpha[2]; accO[i][3] *= alpha[3];
        }
        #pragma unroll
        for (int kk = 0; kk < 2; kk++) {
            bf16x8 a = *(const bf16x8*)(Ps + (wave * 16 + l16) * 64 + kk * 32 + lq * 8);
            #pragma unroll
            for (int nt = 0; nt < 8; nt++) {
                bf16x8 b = *(const bf16x8*)(Vs + (nt * 16 + l16) * 64 + kk * 32 + lq * 8);
                accO[nt] = __builtin_amdgcn_mfma_f32_16x16x32_bf16(a, b, accO[nt], 0, 0, 0);
            }
        }
    }
    float inv[4];
    #pragma unroll
    for (int r = 0; r < 4; r++) inv[r] = 1.f / lrow[r];
    #pragma unroll
    for (int nt = 0; nt < 8; nt++)
        #pragma unroll
        for (int r = 0; r < 4; r++) {
            int row = q0 + wave * 16 + lq * 4 + r;
            concat[(size_t)row * CC + h * 128 + nt * 16 + l16] = (bf16)(accO[nt][r] * inv[r]);
        }
}

// ---------------- launch ----------------
extern "C" void kernel_launch(void* const* d_in, const int* in_sizes, int n_in,
                              void* d_out, int out_size, void* d_ws, size_t ws_size,
                              hipStream_t stream) {
    const float* x       = (const float*)d_in[0];
    const float* vec     = (const float*)d_in[1];
    const float* pe      = (const float*)d_in[2];
    const float* w_mod   = (const float*)d_in[3];
    const float* b_mod   = (const float*)d_in[4];
    const float* w1      = (const float*)d_in[5];
    const float* b1      = (const float*)d_in[6];
    const float* w2      = (const float*)d_in[7];
    const float* b2      = (const float*)d_in[8];
    const float* q_scale = (const float*)d_in[9];
    const float* k_scale = (const float*)d_in[10];
    float* out = (float*)d_out;

    char* ws = (char*)d_ws;
    float* m_buf  = (float*)(ws);
    bf16* x_mod   = (bf16*)(ws + 36864);
    bf16* w1t     = (bf16*)(ws + 12619776);    // reused for w2t after gemm1
    bf16* hqkv    = (bf16*)(ws + 144740352);
    bf16* concat  = (bf16*)(ws + 182489088);
    bf16* q_r     = (bf16*)(ws + 245403648);
    bf16* k_r     = (bf16*)(ws + 257986560);
    bf16* v_t     = (bf16*)(ws + 270569472);

    mod_init_kernel<<<36, 256, 0, stream>>>(b_mod, m_buf);
    mod_gemv_kernel<<<dim3(36, 12), 256, 0, stream>>>(vec, w_mod, m_buf);
    ln_kernel<<<L_SEQ, 256, 0, stream>>>(x, m_buf, x_mod);
    tconv_kernel<<<dim3(N1 / 64, D_MODEL / 64), 256, 0, stream>>>(w1, w1t, D_MODEL, N1);
    gemm_kernel<1><<<dim3(N1 / 128, L_SEQ / 128), 256, 0, stream>>>(
        x_mod, w1t, b1, D_MODEL, hqkv, concat, nullptr, nullptr, nullptr);
    qkv_rope_kernel<<<L_SEQ * N_HEADS / 4, 256, 0, stream>>>(hqkv, pe, q_scale, k_scale, q_r, k_r);
    vtrans_kernel<<<dim3(2, 32, N_HEADS), 256, 0, stream>>>(hqkv, v_t);
    attn_kernel<<<dim3(32, N_HEADS), 256, 0, stream>>>(q_r, k_r, v_t, concat);
    tconv_kernel<<<dim3(D_MODEL / 64, CC / 64), 256, 0, stream>>>(w2, w1t, CC, D_MODEL);
    gemm_kernel<2><<<dim3(D_MODEL / 128, L_SEQ / 128), 256, 0, stream>>>(
        concat, w1t, b2, CC, nullptr, nullptr, x, m_buf + 2 * D_MODEL, out);
}

// Round 2
// 1449.025 us; speedup vs baseline: 1.1388x; 1.1388x over previous
//
#include <hip/hip_runtime.h>

typedef __bf16 bf16;
typedef __bf16 bf16x8 __attribute__((ext_vector_type(8)));
typedef float f32x4 __attribute__((ext_vector_type(4)));

#define L_SEQ   2048
#define D_MODEL 3072
#define N_HEADS 24
#define N1      21504   // QKV + 4D  (gemm1 N)
#define QKV_N   9216
#define CC      15360   // D + 4D    (gemm2 K / concat width)

// ---------------- workspace layout (bytes) ----------------
// m_buf   @ 0          : 9216 f32 (shift|scale|gate)
// x_mod   @ 36864      : 2048x3072 bf16   (LN+modulated, GEMM1 A)
// w1t     @ 12619776   : 21504x3072 bf16  (w1 transposed; later reused for w2t 3072x15360)
// hqkv    @ 144740352  : 2048x9216 bf16   (raw qkv; reused as f32 gemm2 partial p0)
// concat  @ 182489088  : 2048x15360 bf16  (attn | gelu(mlp)) = GEMM2 A
// q_r     @ 245403648  : 24x2048x128 bf16 (with k_r: reused as f32 gemm2 partial p1)
// k_r     @ 257986560  : 24x2048x128 bf16
// v_t     @ 270569472  : 24x128x2048 bf16 (V transposed per head)

__device__ __forceinline__ void async_cp16(const void* g, void* s) {
    __builtin_amdgcn_global_load_lds((const __attribute__((address_space(1))) void*)g,
                                     (__attribute__((address_space(3))) void*)s, 16, 0, 0);
}

// ---------------- modulation GEMV ----------------
__global__ __launch_bounds__(256) void mod_init_kernel(const float* __restrict__ b_mod, float* __restrict__ m) {
    int j = blockIdx.x * 256 + threadIdx.x;
    m[j] = b_mod[j];
}

__global__ __launch_bounds__(256) void mod_gemv_kernel(const float* __restrict__ vec,
                                                       const float* __restrict__ w_mod,
                                                       float* __restrict__ m) {
    int j  = blockIdx.x * 256 + threadIdx.x;
    int d0 = blockIdx.y * 256;
    __shared__ float sv[256];
    float x = vec[d0 + threadIdx.x];
    sv[threadIdx.x] = x / (1.f + __expf(-x));   // silu
    __syncthreads();
    float acc = 0.f;
    #pragma unroll 8
    for (int d = 0; d < 256; d++)
        acc += sv[d] * w_mod[(size_t)(d0 + d) * QKV_N + j];
    atomicAdd(&m[j], acc);
}

// ---------------- layernorm + modulation -> bf16 ----------------
__global__ __launch_bounds__(256) void ln_kernel(const float* __restrict__ x,
                                                 const float* __restrict__ m,
                                                 bf16* __restrict__ x_mod) {
    int l = blockIdx.x, tid = threadIdx.x;
    const float4* xr = (const float4*)(x + (size_t)l * D_MODEL);
    float4 v[3];
    float s = 0.f, ss = 0.f;
    #pragma unroll
    for (int p = 0; p < 3; p++) {
        v[p] = xr[p * 256 + tid];
        s  += v[p].x + v[p].y + v[p].z + v[p].w;
        ss += v[p].x * v[p].x + v[p].y * v[p].y + v[p].z * v[p].z + v[p].w * v[p].w;
    }
    #pragma unroll
    for (int off = 32; off; off >>= 1) { s += __shfl_xor(s, off); ss += __shfl_xor(ss, off); }
    __shared__ float rs[4], rss[4];
    int wave = tid >> 6, lane = tid & 63;
    if (lane == 0) { rs[wave] = s; rss[wave] = ss; }
    __syncthreads();
    s  = rs[0] + rs[1] + rs[2] + rs[3];
    ss = rss[0] + rss[1] + rss[2] + rss[3];
    float mu   = s * (1.f / D_MODEL);
    float var  = ss * (1.f / D_MODEL) - mu * mu;
    float rstd = rsqrtf(var + 1e-6f);
    #pragma unroll
    for (int p = 0; p < 3; p++) {
        int c = (p * 256 + tid) * 4;
        const float* ve = (const float*)&v[p];
        union { bf16 b[4]; uint2 u; } pk;
        #pragma unroll
        for (int e = 0; e < 4; e++) {
            float xn = (ve[e] - mu) * rstd;
            pk.b[e] = (bf16)((1.f + m[D_MODEL + c + e]) * xn + m[c + e]);
        }
        *(uint2*)(x_mod + (size_t)l * D_MODEL + c) = pk.u;
    }
}

// ---------------- transpose + f32->bf16 convert: in (R,C) f32 -> out (C,R) bf16 ----------------
__global__ __launch_bounds__(256) void tconv_kernel(const float* __restrict__ in, bf16* __restrict__ out,
                                                    int R, int C) {
    __shared__ float T[64][65];
    int c0 = blockIdx.x * 64, r0 = blockIdx.y * 64;
    int tid = threadIdx.x;
    int col4 = (tid & 15) * 4, rr = tid >> 4;
    #pragma unroll
    for (int p = 0; p < 4; p++) {
        int r = rr + p * 16;
        float4 v = *(const float4*)(in + (size_t)(r0 + r) * C + c0 + col4);
        T[r][col4 + 0] = v.x; T[r][col4 + 1] = v.y; T[r][col4 + 2] = v.z; T[r][col4 + 3] = v.w;
    }
    __syncthreads();
    int c = tid >> 2, rq = (tid & 3) * 16;
    union { bf16 b[16]; uint4 u[2]; } pk;
    #pragma unroll
    for (int i = 0; i < 16; i++) pk.b[i] = (bf16)T[rq + i][c];
    uint4* op = (uint4*)(out + (size_t)(c0 + c) * R + r0 + rq);
    op[0] = pk.u[0]; op[1] = pk.u[1];
}

// ---------------- m97-style 128x128 bf16 GEMM, Bt is (N,K-major), ld = row stride ----------------
// EPI=1: h = A@W1+b1 -> split qkv / gelu(mlp)->concat   (grid z=1)
// EPI=2: split-K partial f32, blockIdx.z selects K-half and output buffer (grid z=2)
template <int EPI>
__global__ __launch_bounds__(256) void gemm_kernel(
    const bf16* __restrict__ A, const bf16* __restrict__ Bt,
    const float* __restrict__ bias, int K, int ld,
    bf16* __restrict__ o_qkv, bf16* __restrict__ o_concat,
    float* __restrict__ p0, float* __restrict__ p1) {
    __shared__ bf16 As[128 * 32];
    __shared__ bf16 Bs[128 * 32];
    const int tid = threadIdx.x;
    const int wave = tid >> 6, lane = tid & 63;
    const int l16 = lane & 15, lq = lane >> 4;
    const int wm = (wave >> 1) * 64, wn = (wave & 1) * 64;
    const int m0 = blockIdx.y * 128, n0 = blockIdx.x * 128;
    const int koff = (EPI == 2) ? blockIdx.z * K : 0;

    const int srow  = wave * 16 + (lane >> 2);
    const int skoff = (lane & 3) * 8;
    const bf16* Ag = A  + (size_t)(m0 + srow) * ld + koff + skoff;
    const bf16* Bg = Bt + (size_t)(n0 + srow) * ld + koff + skoff;
    bf16* As_w = As + wave * 16 * 32;   // wave-uniform LDS base; HW scatters lane*16B
    bf16* Bs_w = Bs + wave * 16 * 32;

    f32x4 acc[4][4];
    #pragma unroll
    for (int i = 0; i < 4; i++)
        #pragma unroll
        for (int j = 0; j < 4; j++) acc[i][j] = f32x4{0.f, 0.f, 0.f, 0.f};

    for (int k0 = 0; k0 < K; k0 += 32) {
        __syncthreads();
        async_cp16(Ag + k0,                    As_w);
        async_cp16(Ag + k0 + (size_t)64 * ld,  As_w + 64 * 32);
        async_cp16(Bg + k0,                    Bs_w);
        async_cp16(Bg + k0 + (size_t)64 * ld,  Bs_w + 64 * 32);
        __syncthreads();
        bf16x8 af[4], bfr[4];
        #pragma unroll
        for (int i = 0; i < 4; i++) af[i]  = *(const bf16x8*)(As + (wm + 16 * i + l16) * 32 + lq * 8);
        #pragma unroll
        for (int j = 0; j < 4; j++) bfr[j] = *(const bf16x8*)(Bs + (wn + 16 * j + l16) * 32 + lq * 8);
        #pragma unroll
        for (int i = 0; i < 4; i++)
            #pragma unroll
            for (int j = 0; j < 4; j++)
                acc[i][j] = __builtin_amdgcn_mfma_f32_16x16x32_bf16(af[i], bfr[j], acc[i][j], 0, 0, 0);
    }

    float* po = (EPI == 2) ? (blockIdx.z ? p1 : p0) : nullptr;
    #pragma unroll
    for (int i = 0; i < 4; i++) {
        int row = m0 + wm + 16 * i + lq * 4;
        #pragma unroll
        for (int j = 0; j < 4; j++) {
            int col = n0 + wn + 16 * j + l16;
            float bv = (EPI == 1) ? bias[col] : 0.f;
            #pragma unroll
            for (int r = 0; r < 4; r++) {
                float v = acc[i][j][r] + bv;
                int rr = row + r;
                if (EPI == 1) {
                    if (col < QKV_N) {
                        o_qkv[(size_t)rr * QKV_N + col] = (bf16)v;
                    } else {
                        float g = 0.5f * v * (1.f + tanhf(0.7978845608028654f * (v + 0.044715f * v * v * v)));
                        o_concat[(size_t)rr * CC + (col - QKV_N + D_MODEL)] = (bf16)g;
                    }
                } else {
                    po[(size_t)rr * D_MODEL + col] = v;
                }
            }
        }
    }
}

// ---------------- final residual epilogue: out = x + gate*(p0+p1+b2) ----------------
__global__ __launch_bounds__(256) void res_kernel(const float* __restrict__ p0, const float* __restrict__ p1,
                                                  const float* __restrict__ x, const float* __restrict__ gate,
                                                  const float* __restrict__ b2, float* __restrict__ out) {
    int i = blockIdx.x * 256 + threadIdx.x;
    float4 a  = ((const float4*)p0)[i];
    float4 b  = ((const float4*)p1)[i];
    float4 xr = ((const float4*)x)[i];
    int col = (i * 4) % D_MODEL;
    float4 g  = *(const float4*)(gate + col);
    float4 bb = *(const float4*)(b2 + col);
    float4 o;
    o.x = xr.x + g.x * (a.x + b.x + bb.x);
    o.y = xr.y + g.y * (a.y + b.y + bb.y);
    o.z = xr.z + g.z * (a.z + b.z + bb.z);
    o.w = xr.w + g.w * (a.w + b.w + bb.w);
    ((float4*)out)[i] = o;
}

// ---------------- RMSNorm + RoPE for q,k: one wave per (l,head) row ----------------
__global__ __launch_bounds__(256) void qkv_rope_kernel(const bf16* __restrict__ hqkv,
                                                       const float* __restrict__ pe,
                                                       const float* __restrict__ q_scale,
                                                       const float* __restrict__ k_scale,
                                                       bf16* __restrict__ q_r, bf16* __restrict__ k_r) {
    int wave = threadIdx.x >> 6, lane = threadIdx.x & 63;
    int idx = blockIdx.x * 4 + wave;          // 0 .. 2048*24-1
    int l = idx / N_HEADS, h = idx - l * N_HEADS;
    const bf16* qg = hqkv + (size_t)l * QKV_N + h * 128;
    const bf16* kg = qg + D_MODEL;
    float q0 = (float)qg[2 * lane], q1 = (float)qg[2 * lane + 1];
    float k0 = (float)kg[2 * lane], k1 = (float)kg[2 * lane + 1];
    float sq = q0 * q0 + q1 * q1, sk = k0 * k0 + k1 * k1;
    #pragma unroll
    for (int off = 32; off; off >>= 1) { sq += __shfl_xor(sq, off); sk += __shfl_xor(sk, off); }
    float rq = rsqrtf(sq * (1.f / 128.f) + 1e-6f);
    float rk = rsqrtf(sk * (1.f / 128.f) + 1e-6f);
    float s0 = q_scale[2 * lane], s1 = q_scale[2 * lane + 1];
    float z0 = k_scale[2 * lane], z1 = k_scale[2 * lane + 1];
    float4 p = ((const float4*)pe)[(size_t)l * 64 + lane];
    float tq0 = q0 * rq * s0, tq1 = q1 * rq * s1;
    float tk0 = k0 * rk * z0, tk1 = k1 * rk * z1;
    size_t ob = ((size_t)h * L_SEQ + l) * 128 + 2 * lane;
    q_r[ob]     = (bf16)(p.x * tq0 + p.y * tq1);
    q_r[ob + 1] = (bf16)(p.z * tq0 + p.w * tq1);
    k_r[ob]     = (bf16)(p.x * tk0 + p.y * tk1);
    k_r[ob + 1] = (bf16)(p.z * tk0 + p.w * tk1);
}

// ---------------- V transpose: hqkv v-part (l, h*128+d) -> v_t (h, d, l) ----------------
__global__ __launch_bounds__(256) void vtrans_kernel(const bf16* __restrict__ hqkv, bf16* __restrict__ v_t) {
    int dt = blockIdx.x * 64, lt = blockIdx.y * 64, h = blockIdx.z;
    __shared__ bf16 T[64][72];
    int tid = threadIdx.x;
    #pragma unroll
    for (int p = 0; p < 2; p++) {
        int idx = p * 256 + tid;
        int r = idx >> 3, c = idx & 7;
        uint4 v = *(const uint4*)(hqkv + (size_t)(lt + r) * QKV_N + 2 * D_MODEL + h * 128 + dt + c * 8);
        *(uint4*)(&T[r][c * 8]) = v;
    }
    __syncthreads();
    #pragma unroll
    for (int p = 0; p < 2; p++) {
        int idx = p * 256 + tid;
        int d = idx >> 3, c = idx & 7;
        union { bf16 b[8]; uint4 u; } pk;
        #pragma unroll
        for (int i = 0; i < 8; i++) pk.b[i] = T[c * 8 + i][d];
        *(uint4*)(v_t + ((size_t)h * 128 + dt + d) * L_SEQ + lt + c * 8) = pk.u;
    }
}

// ---------------- flash attention: one block per (head, 64 q rows) ----------------
// LDS rows padded: QK_LD=136, VP_LD=72 -> +4 banks/row shift, kills the 16-way conflicts
#define QK_LD 136
#define VP_LD 72
__global__ __launch_bounds__(256) void attn_kernel(const bf16* __restrict__ q_r, const bf16* __restrict__ k_r,
                                                   const bf16* __restrict__ v_t, bf16* __restrict__ concat) {
    const int h = blockIdx.y;
    const int q0 = blockIdx.x * 64;
    __shared__ bf16 Qs[64 * QK_LD];
    __shared__ bf16 Ks[64 * QK_LD];
    __shared__ bf16 Vs[128 * VP_LD];   // V^T tile: [d][key]
    __shared__ bf16 Ps[64 * VP_LD];
    const int tid = threadIdx.x, wave = tid >> 6, lane = tid & 63;
    const int l16 = lane & 15, lq = lane >> 4;
    const bf16* Qg = q_r + ((size_t)h * L_SEQ + q0) * 128;
    const bf16* Kg = k_r + (size_t)h * L_SEQ * 128;
    const bf16* Vg = v_t + (size_t)h * 128 * L_SEQ;
    #pragma unroll
    for (int p = 0; p < 4; p++) {
        int idx = p * 256 + tid, r = idx >> 4, c = idx & 15;
        *(uint4*)(Qs + r * QK_LD + c * 8) = *(const uint4*)(Qg + (size_t)r * 128 + c * 8);
    }
    f32x4 accO[8];
    #pragma unroll
    for (int i = 0; i < 8; i++) accO[i] = f32x4{0.f, 0.f, 0.f, 0.f};
    float mrow[4] = {-1e30f, -1e30f, -1e30f, -1e30f};
    float lrow[4] = {0.f, 0.f, 0.f, 0.f};
    const float sc = 0.08838834764831845f * 1.4426950408889634f;   // 128^-0.5 * log2(e)
    for (int kt = 0; kt < 32; kt++) {
        __syncthreads();
        const bf16* Kt = Kg + (size_t)kt * 64 * 128;
        const bf16* Vt = Vg + kt * 64;
        #pragma unroll
        for (int p = 0; p < 4; p++) {
            int idx = p * 256 + tid, r = idx >> 4, c = idx & 15;
            *(uint4*)(Ks + r * QK_LD + c * 8) = *(const uint4*)(Kt + (size_t)r * 128 + c * 8);
        }
        #pragma unroll
        for (int p = 0; p < 4; p++) {
            int idx = p * 256 + tid, r = idx >> 3, c = idx & 7;
            *(uint4*)(Vs + r * VP_LD + c * 8) = *(const uint4*)(Vt + (size_t)r * L_SEQ + c * 8);
        }
        __syncthreads();
        f32x4 accS[4];
        #pragma unroll
        for (int i = 0; i < 4; i++) accS[i] = f32x4{0.f, 0.f, 0.f, 0.f};
        #pragma unroll
        for (int kk = 0; kk < 4; kk++) {
            bf16x8 a = *(const bf16x8*)(Qs + (wave * 16 + l16) * QK_LD + kk * 32 + lq * 8);
            #pragma unroll
            for (int nt = 0; nt < 4; nt++) {
                bf16x8 b = *(const bf16x8*)(Ks + (nt * 16 + l16) * QK_LD + kk * 32 + lq * 8);
                accS[nt] = __builtin_amdgcn_mfma_f32_16x16x32_bf16(a, b, accS[nt], 0, 0, 0);
            }
        }
        float alpha[4];
        #pragma unroll
        for (int r = 0; r < 4; r++) {
            float x0 = accS[0][r] * sc, x1 = accS[1][r] * sc, x2 = accS[2][r] * sc, x3 = accS[3][r] * sc;
            float mx = fmaxf(fmaxf(x0, x1), fmaxf(x2, x3));
            #pragma unroll
            for (int off = 1; off < 16; off <<= 1) mx = fmaxf(mx, __shfl_xor(mx, off));
            float mnew = fmaxf(mrow[r], mx);
            alpha[r] = __builtin_amdgcn_exp2f(mrow[r] - mnew);
            float p0 = __builtin_amdgcn_exp2f(x0 - mnew), p1 = __builtin_amdgcn_exp2f(x1 - mnew);
            float p2 = __builtin_amdgcn_exp2f(x2 - mnew), p3 = __builtin_amdgcn_exp2f(x3 - mnew);
            float rsum = p0 + p1 + p2 + p3;
            #pragma unroll
            for (int off = 1; off < 16; off <<= 1) rsum += __shfl_xor(rsum, off);
            lrow[r] = lrow[r] * alpha[r] + rsum;
            mrow[r] = mnew;
            int prow = wave * 16 + lq * 4 + r;
            Ps[prow * VP_LD +  0 + l16] = (bf16)p0;
            Ps[prow * VP_LD + 16 + l16] = (bf16)p1;
            Ps[prow * VP_LD + 32 + l16] = (bf16)p2;
            Ps[prow * VP_LD + 48 + l16] = (bf16)p3;
        }
        #pragma unroll
        for (int i = 0; i < 8; i++) {
            accO[i][0] *= alpha[0]; accO[i][1] *= alpha[1];
            accO[i][2] *= alpha[2]; accO[i][3] *= alpha[3];
        }
        #pragma unroll
        for (int kk = 0; kk < 2; kk++) {
            bf16x8 a = *(const bf16x8*)(Ps + (wave * 16 + l16) * VP_LD + kk * 32 + lq * 8);
            #pragma unroll
            for (int nt = 0; nt < 8; nt++) {
                bf16x8 b = *(const bf16x8*)(Vs + (nt * 16 + l16) * VP_LD + kk * 32 + lq * 8);
                accO[nt] = __builtin_amdgcn_mfma_f32_16x16x32_bf16(a, b, accO[nt], 0, 0, 0);
            }
        }
    }
    float inv[4];
    #pragma unroll
    for (int r = 0; r < 4; r++) inv[r] = 1.f / lrow[r];
    #pragma unroll
    for (int nt = 0; nt < 8; nt++)
        #pragma unroll
        for (int r = 0; r < 4; r++) {
            int row = q0 + wave * 16 + lq * 4 + r;
            concat[(size_t)row * CC + h * 128 + nt * 16 + l16] = (bf16)(accO[nt][r] * inv[r]);
        }
}

// ---------------- launch ----------------
extern "C" void kernel_launch(void* const* d_in, const int* in_sizes, int n_in,
                              void* d_out, int out_size, void* d_ws, size_t ws_size,
                              hipStream_t stream) {
    const float* x       = (const float*)d_in[0];
    const float* vec     = (const float*)d_in[1];
    const float* pe      = (const float*)d_in[2];
    const float* w_mod   = (const float*)d_in[3];
    const float* b_mod   = (const float*)d_in[4];
    const float* w1      = (const float*)d_in[5];
    const float* b1      = (const float*)d_in[6];
    const float* w2      = (const float*)d_in[7];
    const float* b2      = (const float*)d_in[8];
    const float* q_scale = (const float*)d_in[9];
    const float* k_scale = (const float*)d_in[10];
    float* out = (float*)d_out;

    char* ws = (char*)d_ws;
    float* m_buf  = (float*)(ws);
    bf16* x_mod   = (bf16*)(ws + 36864);
    bf16* w1t     = (bf16*)(ws + 12619776);    // reused for w2t after gemm1
    bf16* hqkv    = (bf16*)(ws + 144740352);
    bf16* concat  = (bf16*)(ws + 182489088);
    bf16* q_r     = (bf16*)(ws + 245403648);
    bf16* k_r     = (bf16*)(ws + 257986560);
    bf16* v_t     = (bf16*)(ws + 270569472);
    float* p0     = (float*)(ws + 144740352);  // aliases hqkv (dead after attn inputs built)
    float* p1     = (float*)(ws + 245403648);  // aliases q_r+k_r (dead after attn)

    mod_init_kernel<<<36, 256, 0, stream>>>(b_mod, m_buf);
    mod_gemv_kernel<<<dim3(36, 12), 256, 0, stream>>>(vec, w_mod, m_buf);
    ln_kernel<<<L_SEQ, 256, 0, stream>>>(x, m_buf, x_mod);
    tconv_kernel<<<dim3(N1 / 64, D_MODEL / 64), 256, 0, stream>>>(w1, w1t, D_MODEL, N1);
    gemm_kernel<1><<<dim3(N1 / 128, L_SEQ / 128, 1), 256, 0, stream>>>(
        x_mod, w1t, b1, D_MODEL, D_MODEL, hqkv, concat, nullptr, nullptr);
    qkv_rope_kernel<<<L_SEQ * N_HEADS / 4, 256, 0, stream>>>(hqkv, pe, q_scale, k_scale, q_r, k_r);
    vtrans_kernel<<<dim3(2, 32, N_HEADS), 256, 0, stream>>>(hqkv, v_t);
    attn_kernel<<<dim3(32, N_HEADS), 256, 0, stream>>>(q_r, k_r, v_t, concat);
    tconv_kernel<<<dim3(D_MODEL / 64, CC / 64), 256, 0, stream>>>(w2, w1t, CC, D_MODEL);
    gemm_kernel<2><<<dim3(D_MODEL / 128, L_SEQ / 128, 2), 256, 0, stream>>>(
        concat, w1t, nullptr, CC / 2, CC, nullptr, nullptr, p0, p1);
    res_kernel<<<L_SEQ * D_MODEL / 1024, 256, 0, stream>>>(p0, p1, x, m_buf + 2 * D_MODEL, b2, out);
}

// Round 3
// 1324.425 us; speedup vs baseline: 1.2460x; 1.0941x over previous
//
#include <hip/hip_runtime.h>

typedef __bf16 bf16;
typedef __bf16 bf16x8 __attribute__((ext_vector_type(8)));
typedef float f32x4 __attribute__((ext_vector_type(4)));
typedef float f32x16 __attribute__((ext_vector_type(16)));

#define L_SEQ   2048
#define D_MODEL 3072
#define N_HEADS 24
#define N1      21504   // QKV + 4D  (gemm1 N)
#define QKV_N   9216
#define CC      15360   // D + 4D    (gemm2 K / concat width)

// ---------------- workspace layout (bytes) ----------------
// m_buf   @ 0          : 9216 f32 (shift|scale|gate)
// x_mod   @ 36864      : 2048x3072 bf16   (LN+modulated, GEMM1 A)
// w1t     @ 12619776   : 21504x3072 bf16  (w1 transposed; later reused for w2t 3072x15360)
// hqkv    @ 144740352  : 2048x9216 bf16   (raw qkv; reused as f32 gemm2 partial p0)
// concat  @ 182489088  : 2048x15360 bf16  (attn | gelu(mlp)) = GEMM2 A
// q_r     @ 245403648  : 24x2048x128 bf16 (with k_r: reused as f32 gemm2 partial p1)
// k_r     @ 257986560  : 24x2048x128 bf16
// v_t     @ 270569472  : 24x128x2048 bf16 (V transposed per head)

__device__ __forceinline__ void async_cp16(const void* g, void* s) {
    __builtin_amdgcn_global_load_lds((const __attribute__((address_space(1))) void*)g,
                                     (__attribute__((address_space(3))) void*)s, 16, 0, 0);
}

// ---------------- modulation GEMV ----------------
__global__ __launch_bounds__(256) void mod_init_kernel(const float* __restrict__ b_mod, float* __restrict__ m) {
    int j = blockIdx.x * 256 + threadIdx.x;
    m[j] = b_mod[j];
}

__global__ __launch_bounds__(256) void mod_gemv_kernel(const float* __restrict__ vec,
                                                       const float* __restrict__ w_mod,
                                                       float* __restrict__ m) {
    int j  = blockIdx.x * 256 + threadIdx.x;
    int d0 = blockIdx.y * 256;
    __shared__ float sv[256];
    float x = vec[d0 + threadIdx.x];
    sv[threadIdx.x] = x / (1.f + __expf(-x));   // silu
    __syncthreads();
    float acc = 0.f;
    #pragma unroll 8
    for (int d = 0; d < 256; d++)
        acc += sv[d] * w_mod[(size_t)(d0 + d) * QKV_N + j];
    atomicAdd(&m[j], acc);
}

// ---------------- layernorm + modulation -> bf16 ----------------
__global__ __launch_bounds__(256) void ln_kernel(const float* __restrict__ x,
                                                 const float* __restrict__ m,
                                                 bf16* __restrict__ x_mod) {
    int l = blockIdx.x, tid = threadIdx.x;
    const float4* xr = (const float4*)(x + (size_t)l * D_MODEL);
    float4 v[3];
    float s = 0.f, ss = 0.f;
    #pragma unroll
    for (int p = 0; p < 3; p++) {
        v[p] = xr[p * 256 + tid];
        s  += v[p].x + v[p].y + v[p].z + v[p].w;
        ss += v[p].x * v[p].x + v[p].y * v[p].y + v[p].z * v[p].z + v[p].w * v[p].w;
    }
    #pragma unroll
    for (int off = 32; off; off >>= 1) { s += __shfl_xor(s, off); ss += __shfl_xor(ss, off); }
    __shared__ float rs[4], rss[4];
    int wave = tid >> 6, lane = tid & 63;
    if (lane == 0) { rs[wave] = s; rss[wave] = ss; }
    __syncthreads();
    s  = rs[0] + rs[1] + rs[2] + rs[3];
    ss = rss[0] + rss[1] + rss[2] + rss[3];
    float mu   = s * (1.f / D_MODEL);
    float var  = ss * (1.f / D_MODEL) - mu * mu;
    float rstd = rsqrtf(var + 1e-6f);
    #pragma unroll
    for (int p = 0; p < 3; p++) {
        int c = (p * 256 + tid) * 4;
        const float* ve = (const float*)&v[p];
        union { bf16 b[4]; uint2 u; } pk;
        #pragma unroll
        for (int e = 0; e < 4; e++) {
            float xn = (ve[e] - mu) * rstd;
            pk.b[e] = (bf16)((1.f + m[D_MODEL + c + e]) * xn + m[c + e]);
        }
        *(uint2*)(x_mod + (size_t)l * D_MODEL + c) = pk.u;
    }
}

// ---------------- transpose + f32->bf16 convert: in (R,C) f32 -> out (C,R) bf16 ----------------
__global__ __launch_bounds__(256) void tconv_kernel(const float* __restrict__ in, bf16* __restrict__ out,
                                                    int R, int C) {
    __shared__ float T[64][65];
    int c0 = blockIdx.x * 64, r0 = blockIdx.y * 64;
    int tid = threadIdx.x;
    int col4 = (tid & 15) * 4, rr = tid >> 4;
    #pragma unroll
    for (int p = 0; p < 4; p++) {
        int r = rr + p * 16;
        float4 v = *(const float4*)(in + (size_t)(r0 + r) * C + c0 + col4);
        T[r][col4 + 0] = v.x; T[r][col4 + 1] = v.y; T[r][col4 + 2] = v.z; T[r][col4 + 3] = v.w;
    }
    __syncthreads();
    int c = tid >> 2, rq = (tid & 3) * 16;
    union { bf16 b[16]; uint4 u[2]; } pk;
    #pragma unroll
    for (int i = 0; i < 16; i++) pk.b[i] = (bf16)T[rq + i][c];
    uint4* op = (uint4*)(out + (size_t)(c0 + c) * R + r0 + rq);
    op[0] = pk.u[0]; op[1] = pk.u[1];
}

// ---------------- 128x128 tile, BK=64, 32x32x16 MFMA, XOR-swizzled LDS ----------------
// Bt is (N,K-major), ld = row stride.
// EPI=1: h = A@W1+b1 -> split qkv / gelu(mlp)->concat   (grid z=1)
// EPI=2: split-K partial f32, blockIdx.z selects K-half and output buffer (grid z=2)
template <int EPI>
__global__ __launch_bounds__(256, 3) void gemm_kernel(
    const bf16* __restrict__ A, const bf16* __restrict__ Bt,
    const float* __restrict__ bias, int K, int ld,
    bf16* __restrict__ o_qkv, bf16* __restrict__ o_concat,
    float* __restrict__ p0, float* __restrict__ p1) {
    __shared__ bf16 As[128 * 64];
    __shared__ bf16 Bs[128 * 64];
    const int tid = threadIdx.x;
    const int wave = tid >> 6, lane = tid & 63;
    const int l32 = lane & 31, lh = lane >> 5;
    const int wm = (wave >> 1) * 64, wn = (wave & 1) * 64;
    const int m0 = blockIdx.y * 128, n0 = blockIdx.x * 128;
    const int koff = (EPI == 2) ? blockIdx.z * K : 0;

    // staging: instr (wave,i) covers rows i*32+wave*8 .. +7; lane -> row +(lane>>3), 16B chunk (lane&7)
    // XOR swizzle: lane at position c of row r fetches global chunk c^(r&7); r&7 == lane>>3 here
    const int srow_i  = lane >> 3;
    const int schunk  = (lane & 7) ^ srow_i;
    const bf16* Agl = A  + (size_t)(m0 + wave * 8 + srow_i) * ld + koff + schunk * 8;
    const bf16* Bgl = Bt + (size_t)(n0 + wave * 8 + srow_i) * ld + koff + schunk * 8;
    bf16* As_w = As + wave * 8 * 64;
    bf16* Bs_w = Bs + wave * 8 * 64;

    f32x16 acc[2][2];
    #pragma unroll
    for (int i = 0; i < 2; i++)
        #pragma unroll
        for (int j = 0; j < 2; j++)
            #pragma unroll
            for (int e = 0; e < 16; e++) acc[i][j][e] = 0.f;

    const int sw = l32 & 7;   // reader un-swizzle key (rows are l32 mod 32-aligned bases)

    for (int k0 = 0; k0 < K; k0 += 64) {
        __syncthreads();
        #pragma unroll
        for (int i = 0; i < 4; i++) {
            async_cp16(Agl + k0 + (size_t)(i * 32) * ld, As_w + i * 32 * 64);
            async_cp16(Bgl + k0 + (size_t)(i * 32) * ld, Bs_w + i * 32 * 64);
        }
        __syncthreads();
        #pragma unroll
        for (int ks = 0; ks < 4; ks++) {
            const int pos = ((ks * 2 + lh) ^ sw) * 8;
            bf16x8 a0 = *(const bf16x8*)(As + (wm +      l32) * 64 + pos);
            bf16x8 a1 = *(const bf16x8*)(As + (wm + 32 + l32) * 64 + pos);
            bf16x8 b0 = *(const bf16x8*)(Bs + (wn +      l32) * 64 + pos);
            bf16x8 b1 = *(const bf16x8*)(Bs + (wn + 32 + l32) * 64 + pos);
            acc[0][0] = __builtin_amdgcn_mfma_f32_32x32x16_bf16(a0, b0, acc[0][0], 0, 0, 0);
            acc[0][1] = __builtin_amdgcn_mfma_f32_32x32x16_bf16(a0, b1, acc[0][1], 0, 0, 0);
            acc[1][0] = __builtin_amdgcn_mfma_f32_32x32x16_bf16(a1, b0, acc[1][0], 0, 0, 0);
            acc[1][1] = __builtin_amdgcn_mfma_f32_32x32x16_bf16(a1, b1, acc[1][1], 0, 0, 0);
        }
    }

    // C/D layout (32x32): col = lane&31, row = (reg&3) + 8*(reg>>2) + 4*(lane>>5)
    float* po = (EPI == 2) ? (blockIdx.z ? p1 : p0) : nullptr;
    #pragma unroll
    for (int mt = 0; mt < 2; mt++) {
        #pragma unroll
        for (int nt = 0; nt < 2; nt++) {
            int col = n0 + wn + nt * 32 + l32;
            int rbase = m0 + wm + mt * 32 + 4 * lh;
            float bv = (EPI == 1) ? bias[col] : 0.f;
            #pragma unroll
            for (int r = 0; r < 16; r++) {
                int rr = rbase + (r & 3) + 8 * (r >> 2);
                float v = acc[mt][nt][r] + bv;
                if (EPI == 1) {
                    if (col < QKV_N) {
                        o_qkv[(size_t)rr * QKV_N + col] = (bf16)v;
                    } else {
                        float g = 0.5f * v * (1.f + tanhf(0.7978845608028654f * (v + 0.044715f * v * v * v)));
                        o_concat[(size_t)rr * CC + (col - QKV_N + D_MODEL)] = (bf16)g;
                    }
                } else {
                    po[(size_t)rr * D_MODEL + col] = v;
                }
            }
        }
    }
}

// ---------------- final residual epilogue: out = x + gate*(p0+p1+b2) ----------------
__global__ __launch_bounds__(256) void res_kernel(const float* __restrict__ p0, const float* __restrict__ p1,
                                                  const float* __restrict__ x, const float* __restrict__ gate,
                                                  const float* __restrict__ b2, float* __restrict__ out) {
    int i = blockIdx.x * 256 + threadIdx.x;
    float4 a  = ((const float4*)p0)[i];
    float4 b  = ((const float4*)p1)[i];
    float4 xr = ((const float4*)x)[i];
    int col = (i * 4) % D_MODEL;
    float4 g  = *(const float4*)(gate + col);
    float4 bb = *(const float4*)(b2 + col);
    float4 o;
    o.x = xr.x + g.x * (a.x + b.x + bb.x);
    o.y = xr.y + g.y * (a.y + b.y + bb.y);
    o.z = xr.z + g.z * (a.z + b.z + bb.z);
    o.w = xr.w + g.w * (a.w + b.w + bb.w);
    ((float4*)out)[i] = o;
}

// ---------------- RMSNorm + RoPE for q,k: one wave per (l,head) row ----------------
__global__ __launch_bounds__(256) void qkv_rope_kernel(const bf16* __restrict__ hqkv,
                                                       const float* __restrict__ pe,
                                                       const float* __restrict__ q_scale,
                                                       const float* __restrict__ k_scale,
                                                       bf16* __restrict__ q_r, bf16* __restrict__ k_r) {
    int wave = threadIdx.x >> 6, lane = threadIdx.x & 63;
    int idx = blockIdx.x * 4 + wave;          // 0 .. 2048*24-1
    int l = idx / N_HEADS, h = idx - l * N_HEADS;
    const bf16* qg = hqkv + (size_t)l * QKV_N + h * 128;
    const bf16* kg = qg + D_MODEL;
    float q0 = (float)qg[2 * lane], q1 = (float)qg[2 * lane + 1];
    float k0 = (float)kg[2 * lane], k1 = (float)kg[2 * lane + 1];
    float sq = q0 * q0 + q1 * q1, sk = k0 * k0 + k1 * k1;
    #pragma unroll
    for (int off = 32; off; off >>= 1) { sq += __shfl_xor(sq, off); sk += __shfl_xor(sk, off); }
    float rq = rsqrtf(sq * (1.f / 128.f) + 1e-6f);
    float rk = rsqrtf(sk * (1.f / 128.f) + 1e-6f);
    float s0 = q_scale[2 * lane], s1 = q_scale[2 * lane + 1];
    float z0 = k_scale[2 * lane], z1 = k_scale[2 * lane + 1];
    float4 p = ((const float4*)pe)[(size_t)l * 64 + lane];
    float tq0 = q0 * rq * s0, tq1 = q1 * rq * s1;
    float tk0 = k0 * rk * z0, tk1 = k1 * rk * z1;
    size_t ob = ((size_t)h * L_SEQ + l) * 128 + 2 * lane;
    q_r[ob]     = (bf16)(p.x * tq0 + p.y * tq1);
    q_r[ob + 1] = (bf16)(p.z * tq0 + p.w * tq1);
    k_r[ob]     = (bf16)(p.x * tk0 + p.y * tk1);
    k_r[ob + 1] = (bf16)(p.z * tk0 + p.w * tk1);
}

// ---------------- V transpose: hqkv v-part (l, h*128+d) -> v_t (h, d, l) ----------------
__global__ __launch_bounds__(256) void vtrans_kernel(const bf16* __restrict__ hqkv, bf16* __restrict__ v_t) {
    int dt = blockIdx.x * 64, lt = blockIdx.y * 64, h = blockIdx.z;
    __shared__ bf16 T[64][72];
    int tid = threadIdx.x;
    #pragma unroll
    for (int p = 0; p < 2; p++) {
        int idx = p * 256 + tid;
        int r = idx >> 3, c = idx & 7;
        uint4 v = *(const uint4*)(hqkv + (size_t)(lt + r) * QKV_N + 2 * D_MODEL + h * 128 + dt + c * 8);
        *(uint4*)(&T[r][c * 8]) = v;
    }
    __syncthreads();
    #pragma unroll
    for (int p = 0; p < 2; p++) {
        int idx = p * 256 + tid;
        int d = idx >> 3, c = idx & 7;
        union { bf16 b[8]; uint4 u; } pk;
        #pragma unroll
        for (int i = 0; i < 8; i++) pk.b[i] = T[c * 8 + i][d];
        *(uint4*)(v_t + ((size_t)h * 128 + dt + d) * L_SEQ + lt + c * 8) = pk.u;
    }
}

// ---------------- flash attention: one block per (head, 64 q rows); Q in registers ----------------
#define QK_LD 136
#define VP_LD 72
__global__ __launch_bounds__(256) void attn_kernel(const bf16* __restrict__ q_r, const bf16* __restrict__ k_r,
                                                   const bf16* __restrict__ v_t, bf16* __restrict__ concat) {
    const int h = blockIdx.y;
    const int q0 = blockIdx.x * 64;
    __shared__ bf16 Ks[64 * QK_LD];
    __shared__ bf16 Vs[128 * VP_LD];   // V^T tile: [d][key]
    __shared__ bf16 Ps[64 * VP_LD];
    const int tid = threadIdx.x, wave = tid >> 6, lane = tid & 63;
    const int l16 = lane & 15, lq = lane >> 4;
    const bf16* Qg = q_r + ((size_t)h * L_SEQ + q0) * 128;
    const bf16* Kg = k_r + (size_t)h * L_SEQ * 128;
    const bf16* Vg = v_t + (size_t)h * 128 * L_SEQ;
    bf16x8 aq[4];
    #pragma unroll
    for (int kk = 0; kk < 4; kk++)
        aq[kk] = *(const bf16x8*)(Qg + (size_t)(wave * 16 + l16) * 128 + kk * 32 + lq * 8);
    f32x4 accO[8];
    #pragma unroll
    for (int i = 0; i < 8; i++) accO[i] = f32x4{0.f, 0.f, 0.f, 0.f};
    float mrow[4] = {-1e30f, -1e30f, -1e30f, -1e30f};
    float lrow[4] = {0.f, 0.f, 0.f, 0.f};
    const float sc = 0.08838834764831845f * 1.4426950408889634f;   // 128^-0.5 * log2(e)
    for (int kt = 0; kt < 32; kt++) {
        __syncthreads();
        const bf16* Kt = Kg + (size_t)kt * 64 * 128;
        const bf16* Vt = Vg + kt * 64;
        #pragma unroll
        for (int p = 0; p < 4; p++) {
            int idx = p * 256 + tid, r = idx >> 4, c = idx & 15;
            *(uint4*)(Ks + r * QK_LD + c * 8) = *(const uint4*)(Kt + (size_t)r * 128 + c * 8);
        }
        #pragma unroll
        for (int p = 0; p < 4; p++) {
            int idx = p * 256 + tid, r = idx >> 3, c = idx & 7;
            *(uint4*)(Vs + r * VP_LD + c * 8) = *(const uint4*)(Vt + (size_t)r * L_SEQ + c * 8);
        }
        __syncthreads();
        f32x4 accS[4];
        #pragma unroll
        for (int i = 0; i < 4; i++) accS[i] = f32x4{0.f, 0.f, 0.f, 0.f};
        #pragma unroll
        for (int kk = 0; kk < 4; kk++) {
            #pragma unroll
            for (int nt = 0; nt < 4; nt++) {
                bf16x8 b = *(const bf16x8*)(Ks + (nt * 16 + l16) * QK_LD + kk * 32 + lq * 8);
                accS[nt] = __builtin_amdgcn_mfma_f32_16x16x32_bf16(aq[kk], b, accS[nt], 0, 0, 0);
            }
        }
        float alpha[4];
        #pragma unroll
        for (int r = 0; r < 4; r++) {
            float x0 = accS[0][r] * sc, x1 = accS[1][r] * sc, x2 = accS[2][r] * sc, x3 = accS[3][r] * sc;
            float mx = fmaxf(fmaxf(x0, x1), fmaxf(x2, x3));
            #pragma unroll
            for (int off = 1; off < 16; off <<= 1) mx = fmaxf(mx, __shfl_xor(mx, off));
            float mnew = fmaxf(mrow[r], mx);
            alpha[r] = __builtin_amdgcn_exp2f(mrow[r] - mnew);
            float p0 = __builtin_amdgcn_exp2f(x0 - mnew), p1 = __builtin_amdgcn_exp2f(x1 - mnew);
            float p2 = __builtin_amdgcn_exp2f(x2 - mnew), p3 = __builtin_amdgcn_exp2f(x3 - mnew);
            float rsum = p0 + p1 + p2 + p3;
            #pragma unroll
            for (int off = 1; off < 16; off <<= 1) rsum += __shfl_xor(rsum, off);
            lrow[r] = lrow[r] * alpha[r] + rsum;
            mrow[r] = mnew;
            int prow = wave * 16 + lq * 4 + r;
            Ps[prow * VP_LD +  0 + l16] = (bf16)p0;
            Ps[prow * VP_LD + 16 + l16] = (bf16)p1;
            Ps[prow * VP_LD + 32 + l16] = (bf16)p2;
            Ps[prow * VP_LD + 48 + l16] = (bf16)p3;
        }
        #pragma unroll
        for (int i = 0; i < 8; i++) {
            accO[i][0] *= alpha[0]; accO[i][1] *= alpha[1];
            accO[i][2] *= alpha[2]; accO[i][3] *= alpha[3];
        }
        #pragma unroll
        for (int kk = 0; kk < 2; kk++) {
            bf16x8 a = *(const bf16x8*)(Ps + (wave * 16 + l16) * VP_LD + kk * 32 + lq * 8);
            #pragma unroll
            for (int nt = 0; nt < 8; nt++) {
                bf16x8 b = *(const bf16x8*)(Vs + (nt * 16 + l16) * VP_LD + kk * 32 + lq * 8);
                accO[nt] = __builtin_amdgcn_mfma_f32_16x16x32_bf16(a, b, accO[nt], 0, 0, 0);
            }
        }
    }
    float inv[4];
    #pragma unroll
    for (int r = 0; r < 4; r++) inv[r] = 1.f / lrow[r];
    #pragma unroll
    for (int nt = 0; nt < 8; nt++)
        #pragma unroll
        for (int r = 0; r < 4; r++) {
            int row = q0 + wave * 16 + lq * 4 + r;
            concat[(size_t)row * CC + h * 128 + nt * 16 + l16] = (bf16)(accO[nt][r] * inv[r]);
        }
}

// ---------------- launch ----------------
extern "C" void kernel_launch(void* const* d_in, const int* in_sizes, int n_in,
                              void* d_out, int out_size, void* d_ws, size_t ws_size,
                              hipStream_t stream) {
    const float* x       = (const float*)d_in[0];
    const float* vec     = (const float*)d_in[1];
    const float* pe      = (const float*)d_in[2];
    const float* w_mod   = (const float*)d_in[3];
    const float* b_mod   = (const float*)d_in[4];
    const float* w1      = (const float*)d_in[5];
    const float* b1      = (const float*)d_in[6];
    const float* w2      = (const float*)d_in[7];
    const float* b2      = (const float*)d_in[8];
    const float* q_scale = (const float*)d_in[9];
    const float* k_scale = (const float*)d_in[10];
    float* out = (float*)d_out;

    char* ws = (char*)d_ws;
    float* m_buf  = (float*)(ws);
    bf16* x_mod   = (bf16*)(ws + 36864);
    bf16* w1t     = (bf16*)(ws + 12619776);    // reused for w2t after gemm1
    bf16* hqkv    = (bf16*)(ws + 144740352);
    bf16* concat  = (bf16*)(ws + 182489088);
    bf16* q_r     = (bf16*)(ws + 245403648);
    bf16* k_r     = (bf16*)(ws + 257986560);
    bf16* v_t     = (bf16*)(ws + 270569472);
    float* p0     = (float*)(ws + 144740352);  // aliases hqkv (dead after attn inputs built)
    float* p1     = (float*)(ws + 245403648);  // aliases q_r+k_r (dead after attn)

    mod_init_kernel<<<36, 256, 0, stream>>>(b_mod, m_buf);
    mod_gemv_kernel<<<dim3(36, 12), 256, 0, stream>>>(vec, w_mod, m_buf);
    ln_kernel<<<L_SEQ, 256, 0, stream>>>(x, m_buf, x_mod);
    tconv_kernel<<<dim3(N1 / 64, D_MODEL / 64), 256, 0, stream>>>(w1, w1t, D_MODEL, N1);
    gemm_kernel<1><<<dim3(N1 / 128, L_SEQ / 128, 1), 256, 0, stream>>>(
        x_mod, w1t, b1, D_MODEL, D_MODEL, hqkv, concat, nullptr, nullptr);
    qkv_rope_kernel<<<L_SEQ * N_HEADS / 4, 256, 0, stream>>>(hqkv, pe, q_scale, k_scale, q_r, k_r);
    vtrans_kernel<<<dim3(2, 32, N_HEADS), 256, 0, stream>>>(hqkv, v_t);
    attn_kernel<<<dim3(32, N_HEADS), 256, 0, stream>>>(q_r, k_r, v_t, concat);
    tconv_kernel<<<dim3(D_MODEL / 64, CC / 64), 256, 0, stream>>>(w2, w1t, CC, D_MODEL);
    gemm_kernel<2><<<dim3(D_MODEL / 128, L_SEQ / 128, 2), 256, 0, stream>>>(
        concat, w1t, nullptr, CC / 2, CC, nullptr, nullptr, p0, p1);
    res_kernel<<<L_SEQ * D_MODEL / 1024, 256, 0, stream>>>(p0, p1, x, m_buf + 2 * D_MODEL, b2, out);
}